// Round 6
// baseline (99.767 us; speedup 1.0000x reference)
//
#include <hip/hip_runtime.h>
#include <hip/hip_bf16.h>
#include <math.h>

#define N_   4096
#define DIN  512
#define D_   64

typedef __attribute__((ext_vector_type(8))) short  bf16x8;
typedef __attribute__((ext_vector_type(4))) float  f32x4;

__device__ __forceinline__ unsigned short bf16rne(float x) {
    unsigned u = __float_as_uint(x);
    return (unsigned short)((u + 0x7FFFu + ((u >> 16) & 1u)) >> 16);
}
__device__ __forceinline__ unsigned cvt2(float a, float b) {
    __hip_bfloat162 h = __float22bfloat162_rn(make_float2(a, b));
    unsigned u; __builtin_memcpy(&u, &h, 4);
    return u;
}
__device__ __forceinline__ uint2 cvt4(float4 v) {
    return make_uint2(cvt2(v.x, v.y), cvt2(v.z, v.w));
}

// parts-per-tile prefix: S(qi) = sum_{j<qi} ceil(((j>>1)+1)/16); 320 per batch
__device__ __forceinline__ int part_base(int qi) {
    const int m = qi >> 1, e = qi & 1;
    const int k = m >> 4, r = m & 15;
    return 2 * (8 * k * (k + 1) + r * (k + 1)) + e * (k + 1);
}

// ---------------------------------------------------------------------------
// Projection GEMM (unchanged): X fp32 -> {K,Q n-major bf16, Vt o-major bf16}.
// ---------------------------------------------------------------------------
__global__ __launch_bounds__(512) void proj_kernel(
    const float* __restrict__ X, const float* __restrict__ Wk,
    const float* __restrict__ Wq, const float* __restrict__ Wv,
    unsigned short* __restrict__ Kb, unsigned short* __restrict__ Qb,
    unsigned short* __restrict__ Vt)
{
    __shared__ unsigned short Xs[2][64 * 72];
    __shared__ unsigned short Ws[2][192 * 72];

    const int tid  = threadIdx.x;
    const int lane = tid & 63;
    const int w    = tid >> 6;
    const int q15  = lane & 15;
    const int hi   = lane >> 4;
    const int rt   = w >> 1;
    const int oh   = w & 1;
    const int rbase = blockIdx.x * 64;

    float4 xr[2], wr[6];

    auto loadT = [&](int kc) {
        #pragma unroll
        for (int i = 0; i < 2; ++i) {
            const int idx = tid + i * 512;
            xr[i] = *(const float4*)(X + (size_t)(rbase + (idx >> 4)) * DIN + kc + (idx & 15) * 4);
        }
        #pragma unroll
        for (int i = 0; i < 6; ++i) {
            const int idx  = tid + i * 512;
            const int wrow = idx >> 4;
            const float* Wp = (wrow < 64)  ? Wk + (size_t)wrow * DIN
                            : (wrow < 128) ? Wq + (size_t)(wrow - 64) * DIN
                                           : Wv + (size_t)(wrow - 128) * DIN;
            wr[i] = *(const float4*)(Wp + kc + (idx & 15) * 4);
        }
    };
    auto storeT = [&](int p) {
        #pragma unroll
        for (int i = 0; i < 2; ++i) {
            const int idx = tid + i * 512;
            *(uint2*)&Xs[p][(idx >> 4) * 72 + (idx & 15) * 4] = cvt4(xr[i]);
        }
        #pragma unroll
        for (int i = 0; i < 6; ++i) {
            const int idx = tid + i * 512;
            *(uint2*)&Ws[p][(idx >> 4) * 72 + (idx & 15) * 4] = cvt4(wr[i]);
        }
    };

    f32x4 acc[6];
    #pragma unroll
    for (int i = 0; i < 6; ++i) acc[i] = (f32x4){0.f, 0.f, 0.f, 0.f};

    loadT(0);
    int p = 0;
    for (int it = 0; it < 8; ++it) {
        storeT(p);
        __syncthreads();
        if (it < 7) loadT((it + 1) * 64);
        #pragma unroll
        for (int ks = 0; ks < 2; ++ks) {
            bf16x8 af = *(const bf16x8*)&Xs[p][(rt * 16 + q15) * 72 + ks * 32 + hi * 8];
            #pragma unroll
            for (int j = 0; j < 6; ++j) {
                bf16x8 bfr = *(const bf16x8*)&Ws[p][((oh * 6 + j) * 16 + q15) * 72 + ks * 32 + hi * 8];
                acc[j] = __builtin_amdgcn_mfma_f32_16x16x32_bf16(af, bfr, acc[j], 0, 0, 0);
            }
        }
        p ^= 1;
    }

    unsigned short* Os = &Ws[0][0];               // [64n][66o] V staging
    #pragma unroll
    for (int j = 0; j < 6; ++j) {
        const int og = oh * 6 + j;
        #pragma unroll
        for (int r = 0; r < 4; ++r) {
            const int n = rt * 16 + hi * 4 + r;
            const int o = og * 16 + q15;
            unsigned short v = bf16rne(acc[j][r]);
            if (og < 4)      Kb[(size_t)(rbase + n) * D_ + o]        = v;
            else if (og < 8) Qb[(size_t)(rbase + n) * D_ + (o - 64)] = v;
            else             Os[n * 66 + (o - 128)]                  = v;
        }
    }
    __syncthreads();
    {
        const int o  = tid >> 3;
        const int ng = (tid & 7) * 8;
        unsigned short tmp[8];
        #pragma unroll
        for (int i = 0; i < 8; ++i) tmp[i] = Os[(ng + i) * 66 + o];
        const int b  = rbase >> 12;
        const int nb = rbase & (N_ - 1);
        *(uint4*)(Vt + ((size_t)b * D_ + o) * N_ + nb + ng) = *(uint4*)&tmp[0];
    }
}

// ---------------------------------------------------------------------------
// Pass 1: partial attention. Block = (b, 32-row q-tile, k-slice of 16 chunks);
// 4 waves, wave w does chunks {s16+w, s16+w+4, ...} (max 4 steps). No-max
// softmax -> partials purely additive. In-block tree sum -> one fp32 partial
// [32q][64d] + l[32] per block in ws.
// ---------------------------------------------------------------------------
#define PART_F 2080   // 32*64 + 32 floats

__global__ __launch_bounds__(256) void attn_part_kernel(
    const unsigned short* __restrict__ Qb, const unsigned short* __restrict__ Kb,
    const unsigned short* __restrict__ Vt, float* __restrict__ Pws)
{
    __shared__ union {
        unsigned short P[4][32 * 72];             // per-wave P [q][key] bf16
        float Ob2[32 * 68];                       // block partial O [q][d]
    } U;
    __shared__ float Obuf[2][64 * 34];            // combine slots [d][q]
    __shared__ float lb[4][32];

    const int tid  = threadIdx.x;
    const int lane = tid & 63;
    const int w    = tid >> 6;
    const int q15  = lane & 15;
    const int hi   = lane >> 4;

    const int qi = blockIdx.x >> 4;               // 0..127
    const int b  = (blockIdx.x >> 2) & 3;
    const int sl = blockIdx.x & 3;
    const int nch = (qi >> 1) + 1;
    if (sl * 16 >= nch) return;
    const int qb   = qi * 32;
    const int cend = min(nch, sl * 16 + 16);

    const unsigned short* Qp = Qb + (size_t)b * N_ * D_;
    const unsigned short* Kp = Kb + (size_t)b * N_ * D_;
    const unsigned short* Vp = Vt + (size_t)b * D_ * N_;

    bf16x8 qf[2][2];
    #pragma unroll
    for (int qq = 0; qq < 2; ++qq)
        #pragma unroll
        for (int ks = 0; ks < 2; ++ks)
            qf[qq][ks] = *(const bf16x8*)(Qp + (size_t)(qb + qq * 16 + q15) * D_ + ks * 32 + hi * 8);

    f32x4 accO[2][4];
    #pragma unroll
    for (int qq = 0; qq < 2; ++qq)
        #pragma unroll
        for (int dt = 0; dt < 4; ++dt) accO[qq][dt] = (f32x4){0.f, 0.f, 0.f, 0.f};
    float lsum[2] = {0.f, 0.f};

    unsigned short* Pw = &U.P[w][0];
    const float SC = 0.125f * 1.44269504f;        // log2-domain scale

    auto loadK = [&](int c, bf16x8 (&kf)[4][2]) {
        const int kbase = c * 64;
        #pragma unroll
        for (int kt = 0; kt < 4; ++kt)
            #pragma unroll
            for (int ks = 0; ks < 2; ++ks)
                kf[kt][ks] = *(const bf16x8*)(Kp + (size_t)(kbase + kt * 16 + q15) * D_ + ks * 32 + hi * 8);
    };

    auto step = [&](int c, bf16x8 (&cur)[4][2], bf16x8 (&nxt)[4][2]) {
        const int kbase = c * 64;
        const bool last = (c == nch - 1);

        // V loads first: in flight during QK^T + softmax
        bf16x8 vf[2][4];
        #pragma unroll
        for (int ks2 = 0; ks2 < 2; ++ks2)
            #pragma unroll
            for (int dt = 0; dt < 4; ++dt)
                vf[ks2][dt] = *(const bf16x8*)(Vp + (size_t)(dt * 16 + q15) * N_ + kbase + ks2 * 32 + hi * 8);

        // QK^T (swapped) for both q-streams
        f32x4 sv[2][4];
        #pragma unroll
        for (int qq = 0; qq < 2; ++qq)
            #pragma unroll
            for (int kt = 0; kt < 4; ++kt) {
                sv[qq][kt] = (f32x4){0.f, 0.f, 0.f, 0.f};
                #pragma unroll
                for (int ks = 0; ks < 2; ++ks)
                    sv[qq][kt] = __builtin_amdgcn_mfma_f32_16x16x32_bf16(cur[kt][ks], qf[qq][ks], sv[qq][kt], 0, 0, 0);
            }

        // prefetch this wave's next chunk
        if (c + 4 < cend) loadK(c + 4, nxt);

        // softmax-lite: scale, mask (diagonal chunk only), exp2, l, pack
        #pragma unroll
        for (int qq = 0; qq < 2; ++qq) {
            const int qg = qb + qq * 16 + q15;
            #pragma unroll
            for (int kt = 0; kt < 4; ++kt) {
                float p[4];
                #pragma unroll
                for (int r = 0; r < 4; ++r) {
                    float v = sv[qq][kt][r] * SC;
                    if (last) {
                        const int kg = kbase + kt * 16 + hi * 4 + r;
                        v = (kg <= qg) ? v : -INFINITY;
                    }
                    p[r] = __builtin_amdgcn_exp2f(v);
                    lsum[qq] += p[r];
                }
                *(uint2*)&Pw[(qq * 16 + q15) * 72 + kt * 16 + hi * 4] =
                    make_uint2(cvt2(p[0], p[1]), cvt2(p[2], p[3]));
            }
        }

        // PV: O^T += V^T * P^T
        #pragma unroll
        for (int qq = 0; qq < 2; ++qq)
            #pragma unroll
            for (int ks2 = 0; ks2 < 2; ++ks2) {
                bf16x8 pf = *(const bf16x8*)&Pw[(qq * 16 + q15) * 72 + ks2 * 32 + hi * 8];
                #pragma unroll
                for (int dt = 0; dt < 4; ++dt)
                    accO[qq][dt] = __builtin_amdgcn_mfma_f32_16x16x32_bf16(vf[ks2][dt], pf, accO[qq][dt], 0, 0, 0);
            }
    };

    bf16x8 kA[4][2], kB[4][2];
    const int c0 = sl * 16 + w;
    if (c0 < cend) loadK(c0, kA);
    for (int c = c0; c < cend; c += 8) {
        step(c, kA, kB);
        if (c + 4 < cend) step(c + 4, kB, kA);
    }

    // per-wave l reduce
    #pragma unroll
    for (int qq = 0; qq < 2; ++qq) {
        lsum[qq] += __shfl_xor(lsum[qq], 16);
        lsum[qq] += __shfl_xor(lsum[qq], 32);
    }
    if (hi == 0) { lb[w][q15] = lsum[0]; lb[w][16 + q15] = lsum[1]; }

    // pure-sum combine tree -> w0 holds block partial
    if (w >= 2) {
        #pragma unroll
        for (int qq = 0; qq < 2; ++qq)
            #pragma unroll
            for (int dt = 0; dt < 4; ++dt)
                #pragma unroll
                for (int r = 0; r < 4; ++r)
                    Obuf[w - 2][(dt * 16 + hi * 4 + r) * 34 + qq * 16 + q15] = accO[qq][dt][r];
    }
    __syncthreads();
    if (w < 2) {
        #pragma unroll
        for (int qq = 0; qq < 2; ++qq)
            #pragma unroll
            for (int dt = 0; dt < 4; ++dt)
                #pragma unroll
                for (int r = 0; r < 4; ++r)
                    accO[qq][dt][r] += Obuf[w][(dt * 16 + hi * 4 + r) * 34 + qq * 16 + q15];
    }
    __syncthreads();
    if (w == 1) {
        #pragma unroll
        for (int qq = 0; qq < 2; ++qq)
            #pragma unroll
            for (int dt = 0; dt < 4; ++dt)
                #pragma unroll
                for (int r = 0; r < 4; ++r)
                    Obuf[0][(dt * 16 + hi * 4 + r) * 34 + qq * 16 + q15] = accO[qq][dt][r];
    }
    __syncthreads();
    if (w == 0) {
        #pragma unroll
        for (int qq = 0; qq < 2; ++qq)
            #pragma unroll
            for (int dt = 0; dt < 4; ++dt)
                #pragma unroll
                for (int r = 0; r < 4; ++r) {
                    const int d = dt * 16 + hi * 4 + r;
                    U.Ob2[(qq * 16 + q15) * 68 + d] =
                        accO[qq][dt][r] + Obuf[0][d * 34 + qq * 16 + q15];
                }
    }
    __syncthreads();
    // coalesced partial write
    {
        float* partO = Pws + (size_t)(b * 320 + part_base(qi) + sl) * PART_F;
        const int q  = tid >> 3;
        const int d8 = (tid & 7) * 8;
        float4 v0 = *(float4*)&U.Ob2[q * 68 + d8];
        float4 v1 = *(float4*)&U.Ob2[q * 68 + d8 + 4];
        *(float4*)(partO + q * 64 + d8)     = v0;
        *(float4*)(partO + q * 64 + d8 + 4) = v1;
        if (tid < 32)
            partO[2048 + tid] = lb[0][tid] + lb[1][tid] + lb[2][tid] + lb[3][tid];
    }
}

// ---------------------------------------------------------------------------
// Pass 2: sum <=4 partials per (b, q-tile), normalize, write O.
// ---------------------------------------------------------------------------
__global__ __launch_bounds__(256) void attn_merge_kernel(
    const float* __restrict__ Pws, float* __restrict__ O)
{
    const int qi = blockIdx.x >> 2;
    const int b  = blockIdx.x & 3;
    const int nch = (qi >> 1) + 1;
    const int np  = (nch + 15) >> 4;              // <= 4
    const float* base = Pws + (size_t)(b * 320 + part_base(qi)) * PART_F;

    const int tid = threadIdx.x;
    const int q   = tid >> 3;
    const int d8  = (tid & 7) * 8;

    float4 a0 = {0.f, 0.f, 0.f, 0.f}, a1 = {0.f, 0.f, 0.f, 0.f};
    float L = 0.f;
    for (int p = 0; p < np; ++p) {
        const float* pp = base + (size_t)p * PART_F;
        float4 v0 = *(const float4*)(pp + q * 64 + d8);
        float4 v1 = *(const float4*)(pp + q * 64 + d8 + 4);
        a0.x += v0.x; a0.y += v0.y; a0.z += v0.z; a0.w += v0.w;
        a1.x += v1.x; a1.y += v1.y; a1.z += v1.z; a1.w += v1.w;
        L += pp[2048 + q];
    }
    const float rL = 1.0f / L;
    a0.x *= rL; a0.y *= rL; a0.z *= rL; a0.w *= rL;
    a1.x *= rL; a1.y *= rL; a1.z *= rL; a1.w *= rL;
    float* dst = O + ((size_t)b * N_ + qi * 32 + q) * D_ + d8;
    *(float4*)dst       = a0;
    *(float4*)(dst + 4) = a1;
}

// ---------------------------------------------------------------------------
extern "C" void kernel_launch(void* const* d_in, const int* in_sizes, int n_in,
                              void* d_out, int out_size, void* d_ws, size_t ws_size,
                              hipStream_t stream)
{
    const float* x  = (const float*)d_in[0];
    const float* Wk = (const float*)d_in[1];
    const float* Wq = (const float*)d_in[2];
    const float* Wv = (const float*)d_in[3];
    float* O = (float*)d_out;

    const size_t per = (size_t)4 * N_ * D_;       // 1M bf16 elements each
    unsigned short* Kb = (unsigned short*)d_ws;
    unsigned short* Qb = Kb + per;
    unsigned short* Vt = Qb + per;
    float* Pws = (float*)((char*)d_ws + 3 * per * sizeof(unsigned short));

    proj_kernel<<<dim3(4 * N_ / 64), 512, 0, stream>>>(x, Wk, Wq, Wv, Kb, Qb, Vt);
    attn_part_kernel<<<dim3(2048), 256, 0, stream>>>(Qb, Kb, Vt, Pws);
    attn_merge_kernel<<<dim3(512), 256, 0, stream>>>(Pws, O);
}

// Round 7
// 53.207 us; speedup vs baseline: 1.8751x; 1.8751x over previous
//
#include <hip/hip_runtime.h>
#include <hip/hip_bf16.h>
#include <math.h>

#define N_   4096
#define DIN  512
#define D_   64

typedef __attribute__((ext_vector_type(8))) short  bf16x8;
typedef __attribute__((ext_vector_type(4))) float  f32x4;

__device__ __forceinline__ unsigned short bf16rne(float x) {
    unsigned u = __float_as_uint(x);
    return (unsigned short)((u + 0x7FFFu + ((u >> 16) & 1u)) >> 16);
}
__device__ __forceinline__ unsigned cvt2(float a, float b) {
    __hip_bfloat162 h = __float22bfloat162_rn(make_float2(a, b));
    unsigned u; __builtin_memcpy(&u, &h, 4);
    return u;
}
__device__ __forceinline__ uint2 cvt4(float4 v) {
    return make_uint2(cvt2(v.x, v.y), cvt2(v.z, v.w));
}

// slot prefix for 64-row q-tiles, 16-chunk slices:
// pb64(qi) = sum_{j<qi} ceil((j+1)/16); 160 slots per batch
__device__ __forceinline__ int pb64(int qi) {
    const int k = qi >> 4;
    return qi + 16 * (k * (k - 1) / 2) + (qi & 15) * k;
}

#define PART64_F 4160   // 64*64 O^T + 64 l (floats)

// ---------------------------------------------------------------------------
// Projection GEMM (unchanged): X fp32 -> {K,Q n-major bf16, Vt o-major bf16}.
// ---------------------------------------------------------------------------
__global__ __launch_bounds__(512) void proj_kernel(
    const float* __restrict__ X, const float* __restrict__ Wk,
    const float* __restrict__ Wq, const float* __restrict__ Wv,
    unsigned short* __restrict__ Kb, unsigned short* __restrict__ Qb,
    unsigned short* __restrict__ Vt)
{
    __shared__ unsigned short Xs[2][64 * 72];
    __shared__ unsigned short Ws[2][192 * 72];

    const int tid  = threadIdx.x;
    const int lane = tid & 63;
    const int w    = tid >> 6;
    const int q15  = lane & 15;
    const int hi   = lane >> 4;
    const int rt   = w >> 1;
    const int oh   = w & 1;
    const int rbase = blockIdx.x * 64;

    float4 xr[2], wr[6];

    auto loadT = [&](int kc) {
        #pragma unroll
        for (int i = 0; i < 2; ++i) {
            const int idx = tid + i * 512;
            xr[i] = *(const float4*)(X + (size_t)(rbase + (idx >> 4)) * DIN + kc + (idx & 15) * 4);
        }
        #pragma unroll
        for (int i = 0; i < 6; ++i) {
            const int idx  = tid + i * 512;
            const int wrow = idx >> 4;
            const float* Wp = (wrow < 64)  ? Wk + (size_t)wrow * DIN
                            : (wrow < 128) ? Wq + (size_t)(wrow - 64) * DIN
                                           : Wv + (size_t)(wrow - 128) * DIN;
            wr[i] = *(const float4*)(Wp + kc + (idx & 15) * 4);
        }
    };
    auto storeT = [&](int p) {
        #pragma unroll
        for (int i = 0; i < 2; ++i) {
            const int idx = tid + i * 512;
            *(uint2*)&Xs[p][(idx >> 4) * 72 + (idx & 15) * 4] = cvt4(xr[i]);
        }
        #pragma unroll
        for (int i = 0; i < 6; ++i) {
            const int idx = tid + i * 512;
            *(uint2*)&Ws[p][(idx >> 4) * 72 + (idx & 15) * 4] = cvt4(wr[i]);
        }
    };

    f32x4 acc[6];
    #pragma unroll
    for (int i = 0; i < 6; ++i) acc[i] = (f32x4){0.f, 0.f, 0.f, 0.f};

    loadT(0);
    int p = 0;
    for (int it = 0; it < 8; ++it) {
        storeT(p);
        __syncthreads();
        if (it < 7) loadT((it + 1) * 64);
        #pragma unroll
        for (int ks = 0; ks < 2; ++ks) {
            bf16x8 af = *(const bf16x8*)&Xs[p][(rt * 16 + q15) * 72 + ks * 32 + hi * 8];
            #pragma unroll
            for (int j = 0; j < 6; ++j) {
                bf16x8 bfr = *(const bf16x8*)&Ws[p][((oh * 6 + j) * 16 + q15) * 72 + ks * 32 + hi * 8];
                acc[j] = __builtin_amdgcn_mfma_f32_16x16x32_bf16(af, bfr, acc[j], 0, 0, 0);
            }
        }
        p ^= 1;
    }

    unsigned short* Os = &Ws[0][0];               // [64n][66o] V staging
    #pragma unroll
    for (int j = 0; j < 6; ++j) {
        const int og = oh * 6 + j;
        #pragma unroll
        for (int r = 0; r < 4; ++r) {
            const int n = rt * 16 + hi * 4 + r;
            const int o = og * 16 + q15;
            unsigned short v = bf16rne(acc[j][r]);
            if (og < 4)      Kb[(size_t)(rbase + n) * D_ + o]        = v;
            else if (og < 8) Qb[(size_t)(rbase + n) * D_ + (o - 64)] = v;
            else             Os[n * 66 + (o - 128)]                  = v;
        }
    }
    __syncthreads();
    {
        const int o  = tid >> 3;
        const int ng = (tid & 7) * 8;
        unsigned short tmp[8];
        #pragma unroll
        for (int i = 0; i < 8; ++i) tmp[i] = Os[(ng + i) * 66 + o];
        const int b  = rbase >> 12;
        const int nb = rbase & (N_ - 1);
        *(uint4*)(Vt + ((size_t)b * D_ + o) * N_ + nb + ng) = *(uint4*)&tmp[0];
    }
}

// ---------------------------------------------------------------------------
// Pass 1: partial attention. Block = 4 waves x 64 q-rows (wave w owns rows
// w*16..+16), k-slice of <=16 chunks. K/V chunks cooperatively reg-staged
// into padded LDS (coalesced), double-buffered, 1 barrier/chunk; next-chunk
// global loads issue before compute (latency hidden). No-max softmax ->
// additive partials [64d][64q]+l[64] per slice. b = bid&3 pins batch to XCD.
// ---------------------------------------------------------------------------
__global__ __launch_bounds__(256, 3) void attn_part_kernel(
    const unsigned short* __restrict__ Qb, const unsigned short* __restrict__ Kb,
    const unsigned short* __restrict__ Vt, float* __restrict__ Pws)
{
    __shared__ unsigned short Ks[2][64 * 72];
    __shared__ unsigned short Vs[2][64 * 72];
    __shared__ unsigned short Pb[4][16 * 72];

    const int tid  = threadIdx.x;
    const int lane = tid & 63;
    const int w    = tid >> 6;
    const int q15  = lane & 15;
    const int hi   = lane >> 4;

    const int b  = blockIdx.x & 3;                // XCD-pinned batch
    const int qi = (blockIdx.x >> 2) & 63;        // 64-row q-tile
    const int sl = blockIdx.x >> 8;               // k-slice
    const int nch  = qi + 1;
    const int cbeg = sl * 16;
    if (cbeg >= nch) return;
    const int cend = min(nch, cbeg + 16);

    const unsigned short* Qp = Qb + (size_t)b * N_ * D_;
    const unsigned short* Kp = Kb + (size_t)b * N_ * D_;
    const unsigned short* Vp = Vt + (size_t)b * D_ * N_;

    const int qg = qi * 64 + w * 16 + q15;        // this lane's q row
    bf16x8 qf[2];
    #pragma unroll
    for (int ks = 0; ks < 2; ++ks)
        qf[ks] = *(const bf16x8*)(Qp + (size_t)qg * D_ + ks * 32 + hi * 8);

    f32x4 accO[4];
    #pragma unroll
    for (int dt = 0; dt < 4; ++dt) accO[dt] = (f32x4){0.f, 0.f, 0.f, 0.f};
    float lsum = 0.f;

    // cooperative staging: thread -> row tid>>2, 16-elem group (tid&3)*16
    const int srow = tid >> 2;
    const int se0  = (tid & 3) * 16;
    uint4 kr0, kr1, vr0, vr1;

    auto loadC = [&](int c) {
        const int kb2 = c * 64;
        const unsigned short* kp = Kp + (size_t)(kb2 + srow) * D_ + se0;
        kr0 = *(const uint4*)kp;
        kr1 = *(const uint4*)(kp + 8);
        const unsigned short* vp = Vp + (size_t)srow * N_ + kb2 + se0;
        vr0 = *(const uint4*)vp;
        vr1 = *(const uint4*)(vp + 8);
    };
    auto writeC = [&](int p) {
        *(uint4*)&Ks[p][srow * 72 + se0]     = kr0;
        *(uint4*)&Ks[p][srow * 72 + se0 + 8] = kr1;
        *(uint4*)&Vs[p][srow * 72 + se0]     = vr0;
        *(uint4*)&Vs[p][srow * 72 + se0 + 8] = vr1;
    };

    loadC(cbeg);
    writeC(0);
    __syncthreads();

    unsigned short* Pw = &Pb[w][0];
    const float SC = 0.125f * 1.44269504f;        // log2-domain scale
    int p = 0;

    for (int c = cbeg; c < cend; ++c) {
        const int kbase = c * 64;
        if (c + 1 < cend) loadC(c + 1);           // in flight during compute

        // QK^T (swapped): A = K rows from LDS, B = Q^T
        f32x4 sv[4];
        #pragma unroll
        for (int kt = 0; kt < 4; ++kt) {
            bf16x8 k0 = *(const bf16x8*)&Ks[p][(kt * 16 + q15) * 72 + hi * 8];
            bf16x8 k1 = *(const bf16x8*)&Ks[p][(kt * 16 + q15) * 72 + 32 + hi * 8];
            sv[kt] = __builtin_amdgcn_mfma_f32_16x16x32_bf16(k0, qf[0], (f32x4){0.f,0.f,0.f,0.f}, 0, 0, 0);
            sv[kt] = __builtin_amdgcn_mfma_f32_16x16x32_bf16(k1, qf[1], sv[kt], 0, 0, 0);
        }

        // softmax-lite: scale, causal mask, exp2, l, pack -> per-wave P
        #pragma unroll
        for (int kt = 0; kt < 4; ++kt) {
            float pv[4];
            #pragma unroll
            for (int r = 0; r < 4; ++r) {
                float v = sv[kt][r] * SC;
                const int kg = kbase + kt * 16 + hi * 4 + r;
                v = (kg <= qg) ? v : -INFINITY;
                pv[r] = __builtin_amdgcn_exp2f(v);
                lsum += pv[r];
            }
            *(uint2*)&Pw[q15 * 72 + kt * 16 + hi * 4] =
                make_uint2(cvt2(pv[0], pv[1]), cvt2(pv[2], pv[3]));
        }

        // PV: O^T += V^T * P^T (V from LDS)
        #pragma unroll
        for (int ks2 = 0; ks2 < 2; ++ks2) {
            bf16x8 pf = *(const bf16x8*)&Pw[q15 * 72 + ks2 * 32 + hi * 8];
            #pragma unroll
            for (int dt = 0; dt < 4; ++dt) {
                bf16x8 vf = *(const bf16x8*)&Vs[p][(dt * 16 + q15) * 72 + ks2 * 32 + hi * 8];
                accO[dt] = __builtin_amdgcn_mfma_f32_16x16x32_bf16(vf, pf, accO[dt], 0, 0, 0);
            }
        }

        __syncthreads();                          // prev readers of p^1 done
        if (c + 1 < cend) writeC(p ^ 1);
        __syncthreads();                          // staged for next iter
        p ^= 1;
    }

    // l reduce over hi groups (row q15 of this wave)
    lsum += __shfl_xor(lsum, 16);
    lsum += __shfl_xor(lsum, 32);

    // partial write: O^T [64d][64q], wave w owns q-cols w*16..+16
    float* partO = Pws + ((size_t)b * 160 + pb64(qi) + sl) * PART64_F;
    #pragma unroll
    for (int dt = 0; dt < 4; ++dt)
        #pragma unroll
        for (int r = 0; r < 4; ++r)
            partO[(dt * 16 + hi * 4 + r) * 64 + w * 16 + q15] = accO[dt][r];
    if (hi == 0) partO[4096 + w * 16 + q15] = lsum;
}

// ---------------------------------------------------------------------------
// Pass 2: sum <=4 slice partials per (b, 64-row q-tile), transpose via LDS,
// normalize by l, write O.
// ---------------------------------------------------------------------------
__global__ __launch_bounds__(256) void attn_merge_kernel(
    const float* __restrict__ Pws, float* __restrict__ O)
{
    __shared__ float Tr[64 * 68];                 // [d][q]
    __shared__ float Ls[64];

    const int tid = threadIdx.x;
    const int b   = blockIdx.x & 3;
    const int qi  = blockIdx.x >> 2;
    const int np  = (qi + 16) >> 4;               // ceil((qi+1)/16) <= 4
    const float* base = Pws + ((size_t)b * 160 + pb64(qi)) * PART64_F;

    {
        const int d  = tid >> 2;
        const int qg = (tid & 3) * 16;
        float s[16];
        #pragma unroll
        for (int i = 0; i < 16; ++i) s[i] = 0.f;
        for (int pp = 0; pp < np; ++pp) {
            const float* sp = base + (size_t)pp * PART64_F + d * 64 + qg;
            #pragma unroll
            for (int i = 0; i < 4; ++i) {
                float4 v = *(const float4*)(sp + i * 4);
                s[4*i]   += v.x; s[4*i+1] += v.y;
                s[4*i+2] += v.z; s[4*i+3] += v.w;
            }
        }
        #pragma unroll
        for (int i = 0; i < 16; ++i) Tr[d * 68 + qg + i] = s[i];
    }
    if (tid < 64) {
        float L = 0.f;
        for (int pp = 0; pp < np; ++pp) L += base[(size_t)pp * PART64_F + 4096 + tid];
        Ls[tid] = 1.0f / L;
    }
    __syncthreads();
    {
        const int q  = tid >> 2;
        const int dg = (tid & 3) * 16;
        const float rL = Ls[q];
        float ov[16];
        #pragma unroll
        for (int i = 0; i < 16; ++i) ov[i] = Tr[(dg + i) * 68 + q] * rL;
        float* dst = O + ((size_t)b * N_ + qi * 64 + q) * D_ + dg;
        #pragma unroll
        for (int i = 0; i < 4; ++i)
            *(float4*)(dst + i * 4) = make_float4(ov[4*i], ov[4*i+1], ov[4*i+2], ov[4*i+3]);
    }
}

// ---------------------------------------------------------------------------
extern "C" void kernel_launch(void* const* d_in, const int* in_sizes, int n_in,
                              void* d_out, int out_size, void* d_ws, size_t ws_size,
                              hipStream_t stream)
{
    const float* x  = (const float*)d_in[0];
    const float* Wk = (const float*)d_in[1];
    const float* Wq = (const float*)d_in[2];
    const float* Wv = (const float*)d_in[3];
    float* O = (float*)d_out;

    const size_t per = (size_t)4 * N_ * D_;       // 1M bf16 elements each
    unsigned short* Kb = (unsigned short*)d_ws;
    unsigned short* Qb = Kb + per;
    unsigned short* Vt = Qb + per;
    float* Pws = (float*)((char*)d_ws + 3 * per * sizeof(unsigned short));

    proj_kernel<<<dim3(4 * N_ / 64), 512, 0, stream>>>(x, Wk, Wq, Wv, Kb, Qb, Vt);
    attn_part_kernel<<<dim3(1024), 256, 0, stream>>>(Qb, Kb, Vt, Pws);
    attn_merge_kernel<<<dim3(256), 256, 0, stream>>>(Pws, O);
}

// Round 8
// 51.558 us; speedup vs baseline: 1.9350x; 1.0320x over previous
//
#include <hip/hip_runtime.h>
#include <hip/hip_bf16.h>
#include <math.h>

#define N_   4096
#define DIN  512
#define D_   64

typedef __attribute__((ext_vector_type(8))) short  bf16x8;
typedef __attribute__((ext_vector_type(4))) float  f32x4;

__device__ __forceinline__ unsigned short bf16rne(float x) {
    unsigned u = __float_as_uint(x);
    return (unsigned short)((u + 0x7FFFu + ((u >> 16) & 1u)) >> 16);
}
__device__ __forceinline__ unsigned cvt2(float a, float b) {
    __hip_bfloat162 h = __float22bfloat162_rn(make_float2(a, b));
    unsigned u; __builtin_memcpy(&u, &h, 4);
    return u;
}
__device__ __forceinline__ uint2 cvt4(float4 v) {
    return make_uint2(cvt2(v.x, v.y), cvt2(v.z, v.w));
}
// XOR-swizzled short-index for [row][128B] tiles: byte_in_row ^ ((row&7)<<4)
__device__ __forceinline__ int swz(int row, int byte_in_row) {
    return (row * 128 + (byte_in_row ^ ((row & 7) << 4))) >> 1;
}

// slot prefix for 64-row q-tiles, 16-chunk slices: 160 slots per batch
__device__ __forceinline__ int pb64(int qi) {
    const int k = qi >> 4;
    return qi + 16 * (k * (k - 1) / 2) + (qi & 15) * k;
}

#define PART64_F 4160   // 64*64 O^T + 64 l (floats)

// ---------------------------------------------------------------------------
// Projection GEMM: X fp32 -> {K,Q n-major bf16, Vt o-major bf16}.
// 512 thr / 8 waves, BM=64, BK=64, LDS double-buffered, XOR-swizzled tiles.
// ---------------------------------------------------------------------------
__global__ __launch_bounds__(512) void proj_kernel(
    const float* __restrict__ X, const float* __restrict__ Wk,
    const float* __restrict__ Wq, const float* __restrict__ Wv,
    unsigned short* __restrict__ Kb, unsigned short* __restrict__ Qb,
    unsigned short* __restrict__ Vt)
{
    __shared__ unsigned short Xs[2][64 * 64];     // [n][d] swizzled
    __shared__ unsigned short Ws[2][192 * 64];    // [o][d] swizzled

    const int tid  = threadIdx.x;
    const int lane = tid & 63;
    const int w    = tid >> 6;
    const int q15  = lane & 15;
    const int hi   = lane >> 4;
    const int rt   = w >> 1;
    const int oh   = w & 1;
    const int rbase = blockIdx.x * 64;

    float4 xr[2], wr[6];

    auto loadT = [&](int kc) {
        #pragma unroll
        for (int i = 0; i < 2; ++i) {
            const int idx = tid + i * 512;
            xr[i] = *(const float4*)(X + (size_t)(rbase + (idx >> 4)) * DIN + kc + (idx & 15) * 4);
        }
        #pragma unroll
        for (int i = 0; i < 6; ++i) {
            const int idx  = tid + i * 512;
            const int wrow = idx >> 4;
            const float* Wp = (wrow < 64)  ? Wk + (size_t)wrow * DIN
                            : (wrow < 128) ? Wq + (size_t)(wrow - 64) * DIN
                                           : Wv + (size_t)(wrow - 128) * DIN;
            wr[i] = *(const float4*)(Wp + kc + (idx & 15) * 4);
        }
    };
    auto storeT = [&](int p) {
        #pragma unroll
        for (int i = 0; i < 2; ++i) {
            const int idx = tid + i * 512;
            *(uint2*)&Xs[p][swz(idx >> 4, (idx & 15) * 8)] = cvt4(xr[i]);
        }
        #pragma unroll
        for (int i = 0; i < 6; ++i) {
            const int idx = tid + i * 512;
            *(uint2*)&Ws[p][swz(idx >> 4, (idx & 15) * 8)] = cvt4(wr[i]);
        }
    };

    f32x4 acc[6];
    #pragma unroll
    for (int i = 0; i < 6; ++i) acc[i] = (f32x4){0.f, 0.f, 0.f, 0.f};

    loadT(0);
    int p = 0;
    for (int it = 0; it < 8; ++it) {
        storeT(p);
        __syncthreads();
        if (it < 7) loadT((it + 1) * 64);
        #pragma unroll
        for (int ks = 0; ks < 2; ++ks) {
            bf16x8 af = *(const bf16x8*)&Xs[p][swz(rt * 16 + q15, ks * 64 + hi * 16)];
            #pragma unroll
            for (int j = 0; j < 6; ++j) {
                bf16x8 bfr = *(const bf16x8*)&Ws[p][swz((oh * 6 + j) * 16 + q15, ks * 64 + hi * 16)];
                acc[j] = __builtin_amdgcn_mfma_f32_16x16x32_bf16(af, bfr, acc[j], 0, 0, 0);
            }
        }
        p ^= 1;
    }

    unsigned short* Os = &Ws[0][0];               // [64n][66o] V staging (unswizzled scratch)
    #pragma unroll
    for (int j = 0; j < 6; ++j) {
        const int og = oh * 6 + j;
        #pragma unroll
        for (int r = 0; r < 4; ++r) {
            const int n = rt * 16 + hi * 4 + r;
            const int o = og * 16 + q15;
            unsigned short v = bf16rne(acc[j][r]);
            if (og < 4)      Kb[(size_t)(rbase + n) * D_ + o]        = v;
            else if (og < 8) Qb[(size_t)(rbase + n) * D_ + (o - 64)] = v;
            else             Os[n * 66 + (o - 128)]                  = v;
        }
    }
    __syncthreads();
    {
        const int o  = tid >> 3;
        const int ng = (tid & 7) * 8;
        unsigned short tmp[8];
        #pragma unroll
        for (int i = 0; i < 8; ++i) tmp[i] = Os[(ng + i) * 66 + o];
        const int b  = rbase >> 12;
        const int nb = rbase & (N_ - 1);
        *(uint4*)(Vt + ((size_t)b * D_ + o) * N_ + nb + ng) = *(uint4*)&tmp[0];
    }
}

// ---------------------------------------------------------------------------
// Pass 1: partial attention. Block = 4 waves x 64 q-rows, k-slice <=16 chunks.
// K/V chunks reg-staged into XOR-swizzled LDS (coalesced, double-buffered,
// next-chunk loads issued before compute). No-max softmax -> additive
// partials [64d][64q]+l[64]. Compact 640-block grid; b=bid&3 pins batch/XCD.
// ---------------------------------------------------------------------------
__global__ __launch_bounds__(256, 3) void attn_part_kernel(
    const unsigned short* __restrict__ Qb, const unsigned short* __restrict__ Kb,
    const unsigned short* __restrict__ Vt, float* __restrict__ Pws)
{
    __shared__ unsigned short Ks[2][64 * 64];
    __shared__ unsigned short Vs[2][64 * 64];
    __shared__ unsigned short Pb[4][16 * 64];

    const int tid  = threadIdx.x;
    const int lane = tid & 63;
    const int w    = tid >> 6;
    const int q15  = lane & 15;
    const int hi   = lane >> 4;

    const int b = blockIdx.x & 3;                 // XCD-pinned batch
    const int u = blockIdx.x >> 2;                // 0..159
    int sl, qi;
    if      (u < 64)  { sl = 0; qi = 63 - u; }
    else if (u < 112) { sl = 1; qi = 63 - (u - 64); }
    else if (u < 144) { sl = 2; qi = 63 - (u - 112); }
    else              { sl = 3; qi = 63 - (u - 144); }
    const int nch  = qi + 1;
    const int cbeg = sl * 16;
    const int cend = min(nch, cbeg + 16);

    const unsigned short* Qp = Qb + (size_t)b * N_ * D_;
    const unsigned short* Kp = Kb + (size_t)b * N_ * D_;
    const unsigned short* Vp = Vt + (size_t)b * D_ * N_;

    const int qg = qi * 64 + w * 16 + q15;        // this lane's q row
    bf16x8 qf[2];
    #pragma unroll
    for (int ks = 0; ks < 2; ++ks)
        qf[ks] = *(const bf16x8*)(Qp + (size_t)qg * D_ + ks * 32 + hi * 8);

    f32x4 accO[4];
    #pragma unroll
    for (int dt = 0; dt < 4; ++dt) accO[dt] = (f32x4){0.f, 0.f, 0.f, 0.f};
    float lsum = 0.f;

    // cooperative staging: thread -> row tid>>2, byte group (tid&3)*32
    const int srow = tid >> 2;
    const int sb0  = (tid & 3) * 32;
    uint4 kr0, kr1, vr0, vr1;

    auto loadC = [&](int c) {
        const int kb2 = c * 64;
        const unsigned short* kp = Kp + (size_t)(kb2 + srow) * D_ + sb0 / 2;
        kr0 = *(const uint4*)kp;
        kr1 = *(const uint4*)(kp + 8);
        const unsigned short* vp = Vp + (size_t)srow * N_ + kb2 + sb0 / 2;
        vr0 = *(const uint4*)vp;
        vr1 = *(const uint4*)(vp + 8);
    };
    auto writeC = [&](int p) {
        *(uint4*)&Ks[p][swz(srow, sb0)]      = kr0;
        *(uint4*)&Ks[p][swz(srow, sb0 + 16)] = kr1;
        *(uint4*)&Vs[p][swz(srow, sb0)]      = vr0;
        *(uint4*)&Vs[p][swz(srow, sb0 + 16)] = vr1;
    };

    loadC(cbeg);
    writeC(0);
    __syncthreads();

    unsigned short* Pw = &Pb[w][0];
    const float SC = 0.125f * 1.44269504f;        // log2-domain scale
    int p = 0;

    for (int c = cbeg; c < cend; ++c) {
        const int kbase = c * 64;
        if (c + 1 < cend) loadC(c + 1);           // in flight during compute

        // QK^T (swapped): A = K rows from LDS, B = Q^T
        f32x4 sv[4];
        #pragma unroll
        for (int kt = 0; kt < 4; ++kt) {
            bf16x8 k0 = *(const bf16x8*)&Ks[p][swz(kt * 16 + q15, hi * 16)];
            bf16x8 k1 = *(const bf16x8*)&Ks[p][swz(kt * 16 + q15, 64 + hi * 16)];
            sv[kt] = __builtin_amdgcn_mfma_f32_16x16x32_bf16(k0, qf[0], (f32x4){0.f,0.f,0.f,0.f}, 0, 0, 0);
            sv[kt] = __builtin_amdgcn_mfma_f32_16x16x32_bf16(k1, qf[1], sv[kt], 0, 0, 0);
        }

        // softmax-lite: scale, causal mask, exp2, l, pack -> per-wave P
        #pragma unroll
        for (int kt = 0; kt < 4; ++kt) {
            float pv[4];
            #pragma unroll
            for (int r = 0; r < 4; ++r) {
                float v = sv[kt][r] * SC;
                const int kg = kbase + kt * 16 + hi * 4 + r;
                v = (kg <= qg) ? v : -INFINITY;
                pv[r] = __builtin_amdgcn_exp2f(v);
                lsum += pv[r];
            }
            *(uint2*)&Pw[swz(q15, kt * 32 + hi * 8)] =
                make_uint2(cvt2(pv[0], pv[1]), cvt2(pv[2], pv[3]));
        }

        // PV: O^T += V^T * P^T (V from LDS)
        #pragma unroll
        for (int ks2 = 0; ks2 < 2; ++ks2) {
            bf16x8 pf = *(const bf16x8*)&Pw[swz(q15, ks2 * 64 + hi * 16)];
            #pragma unroll
            for (int dt = 0; dt < 4; ++dt) {
                bf16x8 vf = *(const bf16x8*)&Vs[p][swz(dt * 16 + q15, ks2 * 64 + hi * 16)];
                accO[dt] = __builtin_amdgcn_mfma_f32_16x16x32_bf16(vf, pf, accO[dt], 0, 0, 0);
            }
        }

        __syncthreads();                          // prev readers of p^1 done
        if (c + 1 < cend) writeC(p ^ 1);
        __syncthreads();                          // staged for next iter
        p ^= 1;
    }

    // l reduce over hi groups (row q15 of this wave)
    lsum += __shfl_xor(lsum, 16);
    lsum += __shfl_xor(lsum, 32);

    // partial write: O^T [64d][64q], wave w owns q-cols w*16..+16
    float* partO = Pws + ((size_t)b * 160 + pb64(qi) + sl) * PART64_F;
    #pragma unroll
    for (int dt = 0; dt < 4; ++dt)
        #pragma unroll
        for (int r = 0; r < 4; ++r)
            partO[(dt * 16 + hi * 4 + r) * 64 + w * 16 + q15] = accO[dt][r];
    if (hi == 0) partO[4096 + w * 16 + q15] = lsum;
}

// ---------------------------------------------------------------------------
// Pass 2: sum <=4 slice partials per (b, 64-row q-tile), transpose via LDS,
// normalize by l, write O.
// ---------------------------------------------------------------------------
__global__ __launch_bounds__(256) void attn_merge_kernel(
    const float* __restrict__ Pws, float* __restrict__ O)
{
    __shared__ float Tr[64 * 68];                 // [d][q]
    __shared__ float Ls[64];

    const int tid = threadIdx.x;
    const int b   = blockIdx.x & 3;
    const int qi  = blockIdx.x >> 2;
    const int np  = (qi + 16) >> 4;               // ceil((qi+1)/16) <= 4
    const float* base = Pws + ((size_t)b * 160 + pb64(qi)) * PART64_F;

    {
        const int d  = tid >> 2;
        const int qg = (tid & 3) * 16;
        float s[16];
        #pragma unroll
        for (int i = 0; i < 16; ++i) s[i] = 0.f;
        for (int pp = 0; pp < np; ++pp) {
            const float* sp = base + (size_t)pp * PART64_F + d * 64 + qg;
            #pragma unroll
            for (int i = 0; i < 4; ++i) {
                float4 v = *(const float4*)(sp + i * 4);
                s[4*i]   += v.x; s[4*i+1] += v.y;
                s[4*i+2] += v.z; s[4*i+3] += v.w;
            }
        }
        #pragma unroll
        for (int i = 0; i < 16; ++i) Tr[d * 68 + qg + i] = s[i];
    }
    if (tid < 64) {
        float L = 0.f;
        for (int pp = 0; pp < np; ++pp) L += base[(size_t)pp * PART64_F + 4096 + tid];
        Ls[tid] = 1.0f / L;
    }
    __syncthreads();
    {
        const int q  = tid >> 2;
        const int dg = (tid & 3) * 16;
        const float rL = Ls[q];
        float ov[16];
        #pragma unroll
        for (int i = 0; i < 16; ++i) ov[i] = Tr[(dg + i) * 68 + q] * rL;
        float* dst = O + ((size_t)b * N_ + qi * 64 + q) * D_ + dg;
        #pragma unroll
        for (int i = 0; i < 4; ++i)
            *(float4*)(dst + i * 4) = make_float4(ov[4*i], ov[4*i+1], ov[4*i+2], ov[4*i+3]);
    }
}

// ---------------------------------------------------------------------------
extern "C" void kernel_launch(void* const* d_in, const int* in_sizes, int n_in,
                              void* d_out, int out_size, void* d_ws, size_t ws_size,
                              hipStream_t stream)
{
    const float* x  = (const float*)d_in[0];
    const float* Wk = (const float*)d_in[1];
    const float* Wq = (const float*)d_in[2];
    const float* Wv = (const float*)d_in[3];
    float* O = (float*)d_out;

    const size_t per = (size_t)4 * N_ * D_;       // 1M bf16 elements each
    unsigned short* Kb = (unsigned short*)d_ws;
    unsigned short* Qb = Kb + per;
    unsigned short* Vt = Qb + per;
    float* Pws = (float*)((char*)d_ws + 3 * per * sizeof(unsigned short));

    proj_kernel<<<dim3(4 * N_ / 64), 512, 0, stream>>>(x, Wk, Wq, Wv, Kb, Qb, Vt);
    attn_part_kernel<<<dim3(640), 256, 0, stream>>>(Qb, Kb, Vt, Pws);
    attn_merge_kernel<<<dim3(256), 256, 0, stream>>>(Pws, O);
}